// Round 3
// baseline (1791.995 us; speedup 1.0000x reference)
//
#include <hip/hip_runtime.h>

#define NB 2
#define CIN 64
#define DD 12
#define HWP 800
#define NPOS 9600   // DD*HWP
#define CT 32
#define SAMP 19200  // NB*NPOS
#define SCALE 0.17677669529663687f  // 1/sqrt(32)

// ---------- K1: per-pixel softmax over D, argmax, gathered prob ----------
__global__ __launch_bounds__(256) void prep_kernel(const float* __restrict__ preds,
                                                   int* __restrict__ a, float* __restrict__ pv)
{
    int idx = blockIdx.x*256 + threadIdx.x;
    if (idx >= NB*HWP) return;
    int b = idx / HWP, pix = idx % HWP;
    const float* p = preds + (size_t)b*DD*HWP + pix;
    float mx = -INFINITY; int am = 0;
    #pragma unroll
    for (int d=0; d<DD; ++d){ float v = p[d*HWP]; if (v > mx){ mx=v; am=d; } }
    float s = 0.f;
    #pragma unroll
    for (int d=0; d<DD; ++d) s += __expf(p[d*HWP]-mx);
    a[idx] = am; pv[idx] = 1.f/s;   // p[argmax] = exp(0)/s
}

// ---------- K2: segment softmax over pixels sharing argmax class ----------
__global__ __launch_bounds__(256) void seg_kernel(const float* __restrict__ pv,
                                                  const int* __restrict__ a, float* __restrict__ wt)
{
    int b = blockIdx.x / DD, seg = blockIdx.x % DD;
    int base = b*HWP;
    __shared__ float red[256];
    int t = threadIdx.x;
    float mx = -INFINITY;
    for (int i=t; i<HWP; i+=256) if (a[base+i]==seg) mx = fmaxf(mx, pv[base+i]);
    red[t]=mx; __syncthreads();
    for (int s=128; s>0; s>>=1){ if (t<s) red[t]=fmaxf(red[t],red[t+s]); __syncthreads(); }
    float m = red[0]; __syncthreads();
    if (m == -INFINITY) return;           // empty segment (uniform branch)
    float sm = 0.f;
    for (int i=t; i<HWP; i+=256) if (a[base+i]==seg) sm += __expf(pv[base+i]-m);
    red[t]=sm; __syncthreads();
    for (int s=128; s>0; s>>=1){ if (t<s) red[t]+=red[t+s]; __syncthreads(); }
    float ssum = red[0];
    for (int i=t; i<HWP; i+=256) if (a[base+i]==seg) wt[base+i] = __expf(pv[base+i]-m)/ssum;
}

// ---------- K3: fused conv1: q1 = Wq1@x, k1 = fac*(Wk1@x), v = fac*(Wv@x) ----------
__global__ __launch_bounds__(256) void conv1_kernel(const float* __restrict__ x,
    const int* __restrict__ a, const float* __restrict__ wt,
    const float* __restrict__ Wq1, const float* __restrict__ Wk1, const float* __restrict__ Wv,
    float* __restrict__ q1, float* __restrict__ k1, float* __restrict__ v1)
{
    __shared__ float lw[6144];
    for (int i=threadIdx.x; i<2048; i+=256){ lw[i]=Wq1[i]; lw[2048+i]=Wk1[i]; lw[4096+i]=Wv[i]; }
    __syncthreads();
    int t = threadIdx.x;
    int posIdx = blockIdx.x*64 + (t&63);
    int g = t>>6;                      // 4 channel-groups of 24
    int b = posIdx / NPOS, pos = posIdx % NPOS;
    int d = pos / HWP, pix = pos % HWP;
    float fac = 1.f;
    if (a[b*HWP+pix] == d) fac += wt[b*HWP+pix];
    float acc[24];
    #pragma unroll
    for (int j=0;j<24;++j) acc[j]=0.f;
    const float* xb = x + (size_t)b*CIN*NPOS + pos;
    int chBase = g*24;
    for (int c=0;c<CIN;++c){
        float xv = xb[(size_t)c*NPOS];
        const float* wrow = &lw[chBase*64 + c];
        #pragma unroll
        for (int j=0;j<24;++j) acc[j] += xv * wrow[j*64];
    }
    #pragma unroll
    for (int j=0;j<24;++j){
        int ch = chBase + j;
        float val = acc[j];
        if (ch < 32)       q1[((size_t)b*CT + ch)*NPOS + pos] = val;
        else if (ch < 64)  k1[((size_t)b*CT + (ch-32))*NPOS + pos] = val*fac;
        else               v1[((size_t)b*CT + (ch-64))*NPOS + pos] = val*fac;
    }
}

// ---------- per-channel BN stats: mu, rsqrt(var+eps) ----------
__global__ __launch_bounds__(256) void stats_kernel(const float* __restrict__ src,
                                                    float* __restrict__ mu, float* __restrict__ rs, int C)
{
    int ch = blockIdx.x;
    float sum=0.f, sq=0.f;
    for (int i=threadIdx.x; i<SAMP; i+=256){
        int b = i/NPOS; int pos = i - b*NPOS;
        float v = src[((size_t)b*C + ch)*NPOS + pos];
        sum += v; sq += v*v;
    }
    for (int off=32; off; off>>=1){ sum += __shfl_down(sum,off); sq += __shfl_down(sq,off); }
    __shared__ float ls[4], lq[4];
    int wv = threadIdx.x>>6, lane = threadIdx.x&63;
    if (lane==0){ ls[wv]=sum; lq[wv]=sq; }
    __syncthreads();
    if (threadIdx.x==0){
        float S = ls[0]+ls[1]+ls[2]+ls[3];
        float Q = lq[0]+lq[1]+lq[2]+lq[3];
        float m = S/(float)SAMP;
        float var = Q/(float)SAMP - m*m;
        mu[ch]=m; rs[ch]=rsqrtf(var + 1e-5f);
    }
}

// ---------- K5: conv2 (BN+ReLU of inputs fused): q2 = Wq2@bnrelu(q1), k2 = Wk2@bnrelu(k1) ----------
__global__ __launch_bounds__(256) void conv2_kernel(const float* __restrict__ q1, const float* __restrict__ k1,
    const float* __restrict__ Wq2, const float* __restrict__ Wk2,
    const float* __restrict__ mu1, const float* __restrict__ rs1,
    float* __restrict__ q2, float* __restrict__ k2)
{
    __shared__ float lw[2048];
    for (int i=threadIdx.x; i<1024; i+=256){ lw[i]=Wq2[i]; lw[1024+i]=Wk2[i]; }
    __syncthreads();
    int t = threadIdx.x;
    int posIdx = blockIdx.x*64 + (t&63);
    int g = t>>6;
    int b = posIdx / NPOS, pos = posIdx % NPOS;
    const float* src = (g<2) ? q1 : k1;
    const float* wb  = (g<2) ? lw : (lw+1024);
    float* dst       = (g<2) ? q2 : k2;
    int so = (g<2) ? 0 : 32;
    int chBase = (g&1)*16;
    float acc[16];
    #pragma unroll
    for (int j=0;j<16;++j) acc[j]=0.f;
    for (int c=0;c<32;++c){
        float v = src[((size_t)b*CT + c)*NPOS + pos];
        float vn = fmaxf((v - mu1[so+c])*rs1[so+c], 0.f);
        const float* wrow = &wb[chBase*32 + c];
        #pragma unroll
        for (int j=0;j<16;++j) acc[j] += vn * wrow[j*32];
    }
    #pragma unroll
    for (int j=0;j<16;++j)
        dst[((size_t)b*CT + chBase + j)*NPOS + pos] = acc[j];
}

// ---------- elementwise BN+ReLU ----------
__global__ __launch_bounds__(256) void bn_relu_kernel(const float* __restrict__ src,
    const float* __restrict__ mu, const float* __restrict__ rs,
    float* __restrict__ dst, int C, int total)
{
    int idx = blockIdx.x*256 + threadIdx.x;
    if (idx >= total) return;
    int ch = (idx / NPOS) % C;
    dst[idx] = fmaxf((src[idx]-mu[ch])*rs[ch], 0.f);
}

// ---------- K7: flash attention, fp32. 32 queries/wg, 8 key-phases (4 waves x lane-half) ----------
__global__ __launch_bounds__(256) void attn_kernel(const float* __restrict__ q2, const float* __restrict__ k2,
    const float* __restrict__ vn, const float* __restrict__ mu2, const float* __restrict__ rs2,
    float* __restrict__ ctx)
{
    __shared__ __align__(16) float kb[2304];   // [8 phases][8 keys][36]
    __shared__ __align__(16) float vb[2304];
    __shared__ float mbuf[3264];               // [3 waves][32 q][34]
    int blk = blockIdx.x;
    int b = blk / 300, qb = blk % 300;         // 300 query-blocks (32 q each) per batch
    int q0 = qb * 32;
    int t = threadIdx.x;
    int lane = t & 63, wv = t >> 6;
    int h = lane >> 5, ql = lane & 31;
    int phase = wv*2 + h;
    int qg = q0 + ql;
    const float* qbase = q2 + (size_t)b*CT*NPOS;
    const float* kbase = k2 + (size_t)b*CT*NPOS;
    const float* vbase = vn + (size_t)b*CT*NPOS;
    float q[32];
    #pragma unroll
    for (int c=0;c<32;++c){
        float v = qbase[(size_t)c*NPOS + qg];
        q[c] = fmaxf((v - mu2[c])*rs2[c], 0.f) * SCALE;
    }
    float m = -INFINITY, l = 0.f;
    float acc[32];
    #pragma unroll
    for (int c=0;c<32;++c) acc[c]=0.f;

    for (int chunk=0; chunk<150; ++chunk){
        int c0 = chunk*8;
        // wave stages its two phases' next 8 keys (normalized K, raw V)
        #pragma unroll
        for (int i=0;i<8;++i){
            int idx = i*64 + lane;             // 0..511
            int ph = idx >> 8;                 // 0..1
            int cc = (idx >> 3) & 31;
            int kk = idx & 7;
            int keyg = (wv*2+ph)*1200 + c0 + kk;
            int lidx = ((wv*2+ph)*8 + kk)*36 + cc;
            float kvv = kbase[(size_t)cc*NPOS + keyg];
            kb[lidx] = fmaxf((kvv - mu2[32+cc])*rs2[32+cc], 0.f);
            vb[lidx] = vbase[(size_t)cc*NPOS + keyg];
        }
        __syncthreads();
        float s[8];
        #pragma unroll
        for (int kk=0;kk<8;++kk){
            const float4* kr = (const float4*)&kb[(phase*8+kk)*36];
            float dot = 0.f;
            #pragma unroll
            for (int cc=0;cc<8;++cc){
                float4 kv = kr[cc];
                dot += q[cc*4+0]*kv.x + q[cc*4+1]*kv.y + q[cc*4+2]*kv.z + q[cc*4+3]*kv.w;
            }
            s[kk] = dot;
        }
        float mt = s[0];
        #pragma unroll
        for (int kk=1;kk<8;++kk) mt = fmaxf(mt, s[kk]);
        float mnew = fmaxf(m, mt);
        float corr = __expf(m - mnew);         // m=-inf on first chunk -> 0
        l *= corr;
        #pragma unroll
        for (int c=0;c<32;++c) acc[c] *= corr;
        #pragma unroll
        for (int kk=0;kk<8;++kk){
            float p = __expf(s[kk]-mnew);
            l += p;
            const float4* vr = (const float4*)&vb[(phase*8+kk)*36];
            #pragma unroll
            for (int cc=0;cc<8;++cc){
                float4 vv = vr[cc];
                acc[cc*4+0] += p*vv.x; acc[cc*4+1] += p*vv.y;
                acc[cc*4+2] += p*vv.z; acc[cc*4+3] += p*vv.w;
            }
        }
        m = mnew;
        __syncthreads();
    }
    // merge lane-halves within wave
    {
        float m2 = __shfl_xor(m, 32);
        float l2 = __shfl_xor(l, 32);
        float mn = fmaxf(m, m2);
        float cA = __expf(m - mn), cB = __expf(m2 - mn);
        l = l*cA + l2*cB;
        #pragma unroll
        for (int c=0;c<32;++c){
            float a2 = __shfl_xor(acc[c], 32);
            acc[c] = acc[c]*cA + a2*cB;
        }
        m = mn;
    }
    // merge across waves via LDS
    if (wv > 0 && lane < 32){
        float* mb = &mbuf[((wv-1)*32 + ql)*34];
        mb[0]=m; mb[1]=l;
        #pragma unroll
        for (int c=0;c<32;++c) mb[2+c]=acc[c];
    }
    __syncthreads();
    if (wv == 0 && lane < 32){
        for (int w=0;w<3;++w){
            const float* mb = &mbuf[(w*32 + ql)*34];
            float m2=mb[0], l2=mb[1];
            float mn = fmaxf(m, m2);
            float cA = __expf(m-mn), cB = __expf(m2-mn);
            l = l*cA + l2*cB;
            #pragma unroll
            for (int c=0;c<32;++c) acc[c] = acc[c]*cA + mb[2+c]*cB;
            m = mn;
        }
        float inv = 1.f/l;
        #pragma unroll
        for (int c=0;c<32;++c)
            ctx[((size_t)b*CT + c)*NPOS + qg] = acc[c]*inv;
    }
}

// ---------- K8: out conv (raw): outraw = Wo @ ctx ----------
__global__ __launch_bounds__(256) void convo_kernel(const float* __restrict__ ctx,
    const float* __restrict__ Wo, float* __restrict__ outraw)
{
    __shared__ float lw[2048];
    for (int i=threadIdx.x; i<2048; i+=256) lw[i]=Wo[i];
    __syncthreads();
    int t = threadIdx.x;
    int posIdx = blockIdx.x*64 + (t&63);
    int g = t>>6;
    int b = posIdx / NPOS, pos = posIdx % NPOS;
    int chBase = g*16;
    float acc[16];
    #pragma unroll
    for (int j=0;j<16;++j) acc[j]=0.f;
    for (int c=0;c<32;++c){
        float v = ctx[((size_t)b*CT + c)*NPOS + pos];
        const float* wrow = &lw[chBase*32 + c];
        #pragma unroll
        for (int j=0;j<16;++j) acc[j] += v * wrow[j*32];
    }
    #pragma unroll
    for (int j=0;j<16;++j)
        outraw[((size_t)b*64 + chBase + j)*NPOS + pos] = acc[j];
}

extern "C" void kernel_launch(void* const* d_in, const int* in_sizes, int n_in,
                              void* d_out, int out_size, void* d_ws, size_t ws_size,
                              hipStream_t stream)
{
    const float* x     = (const float*)d_in[0];
    const float* preds = (const float*)d_in[1];
    const float* Wq1   = (const float*)d_in[2];
    const float* Wq2   = (const float*)d_in[3];
    const float* Wk1   = (const float*)d_in[4];
    const float* Wk2   = (const float*)d_in[5];
    const float* Wv    = (const float*)d_in[6];
    const float* Wo    = (const float*)d_in[7];
    float* out = (float*)d_out;

    float* w     = (float*)d_ws;
    int*   a_idx = (int*)d_ws;            // [0, 1600)
    float* pv    = w + 2048;
    float* wt    = w + 4096;
    float* mu1   = w + 6656;  // 96
    float* rs1   = w + 6752;  // 96
    float* mu2   = w + 6848;  // 64 (q2:0..31, k2:32..63)
    float* rs2   = w + 6912;
    float* muo   = w + 6976;
    float* rso   = w + 7040;
    float* q1    = w + 8192;      // 614400 each
    float* k1    = w + 622592;
    float* v1    = w + 1236992;
    float* q2    = w + 1851392;
    float* k2    = w + 2465792;
    float* vnb   = w + 3080192;
    float* ctx    = q1;           // q1 dead after conv2
    float* outraw = k1;           // k1+v1 slots dead after attention (1228800 floats)

    prep_kernel <<<7,   256,0,stream>>>(preds, a_idx, pv);
    seg_kernel  <<<24,  256,0,stream>>>(pv, a_idx, wt);
    conv1_kernel<<<300, 256,0,stream>>>(x, a_idx, wt, Wq1, Wk1, Wv, q1, k1, v1);
    stats_kernel<<<32,  256,0,stream>>>(q1, mu1,    rs1,    32);
    stats_kernel<<<32,  256,0,stream>>>(k1, mu1+32, rs1+32, 32);
    stats_kernel<<<32,  256,0,stream>>>(v1, mu1+64, rs1+64, 32);
    conv2_kernel<<<300, 256,0,stream>>>(q1, k1, Wq2, Wk2, mu1, rs1, q2, k2);
    bn_relu_kernel<<<2400,256,0,stream>>>(v1, mu1+64, rs1+64, vnb, 32, 614400);
    stats_kernel<<<32,  256,0,stream>>>(q2, mu2,    rs2,    32);
    stats_kernel<<<32,  256,0,stream>>>(k2, mu2+32, rs2+32, 32);
    attn_kernel <<<600, 256,0,stream>>>(q2, k2, vnb, mu2, rs2, ctx);
    convo_kernel<<<300, 256,0,stream>>>(ctx, Wo, outraw);
    stats_kernel<<<64,  256,0,stream>>>(outraw, muo, rso, 64);
    bn_relu_kernel<<<4800,256,0,stream>>>(outraw, muo, rso, out, 64, 1228800);
}

// Round 4
// 333.826 us; speedup vs baseline: 5.3681x; 5.3681x over previous
//
#include <hip/hip_runtime.h>

#define NB 2
#define CIN 64
#define DD 12
#define HWP 800
#define NPOS 9600   // DD*HWP
#define CT 32
#define SAMP 19200  // NB*NPOS
#define QKSCALE 0.25506601f   // (1/sqrt(32)) * log2(e)  folded into Q pack
#define CSH 11.541560327f     // 8 * log2(e): P = exp2(S*log2e - CSH) = exp(S - 8)

typedef __attribute__((ext_vector_type(8))) short short8;
typedef __attribute__((ext_vector_type(4))) float f32x4;

__device__ __forceinline__ ushort f2bf(float x){
    union { float f; unsigned u; } v; v.f = x;
    unsigned r = v.u + 0x7fffu + ((v.u >> 16) & 1u);   // RNE
    return (ushort)(r >> 16);
}

// ---------- K1: per-pixel softmax over D, argmax, gathered prob ----------
__global__ __launch_bounds__(256) void prep_kernel(const float* __restrict__ preds,
                                                   int* __restrict__ a, float* __restrict__ pv)
{
    int idx = blockIdx.x*256 + threadIdx.x;
    if (idx >= NB*HWP) return;
    int b = idx / HWP, pix = idx % HWP;
    const float* p = preds + (size_t)b*DD*HWP + pix;
    float mx = -INFINITY; int am = 0;
    #pragma unroll
    for (int d=0; d<DD; ++d){ float v = p[d*HWP]; if (v > mx){ mx=v; am=d; } }
    float s = 0.f;
    #pragma unroll
    for (int d=0; d<DD; ++d) s += __expf(p[d*HWP]-mx);
    a[idx] = am; pv[idx] = 1.f/s;   // p[argmax] = exp(0)/s
}

// ---------- K2: segment softmax over pixels sharing argmax class ----------
__global__ __launch_bounds__(256) void seg_kernel(const float* __restrict__ pv,
                                                  const int* __restrict__ a, float* __restrict__ wt)
{
    int b = blockIdx.x / DD, seg = blockIdx.x % DD;
    int base = b*HWP;
    __shared__ float red[256];
    int t = threadIdx.x;
    float mx = -INFINITY;
    for (int i=t; i<HWP; i+=256) if (a[base+i]==seg) mx = fmaxf(mx, pv[base+i]);
    red[t]=mx; __syncthreads();
    for (int s=128; s>0; s>>=1){ if (t<s) red[t]=fmaxf(red[t],red[t+s]); __syncthreads(); }
    float m = red[0]; __syncthreads();
    if (m == -INFINITY) return;           // empty segment (uniform branch)
    float sm = 0.f;
    for (int i=t; i<HWP; i+=256) if (a[base+i]==seg) sm += __expf(pv[base+i]-m);
    red[t]=sm; __syncthreads();
    for (int s=128; s>0; s>>=1){ if (t<s) red[t]+=red[t+s]; __syncthreads(); }
    float ssum = red[0];
    for (int i=t; i<HWP; i+=256) if (a[base+i]==seg) wt[base+i] = __expf(pv[base+i]-m)/ssum;
}

// ---------- K3: fused conv1: q1 = Wq1@x, k1 = fac*(Wk1@x), v = fac*(Wv@x) ----------
__global__ __launch_bounds__(256) void conv1_kernel(const float* __restrict__ x,
    const int* __restrict__ a, const float* __restrict__ wt,
    const float* __restrict__ Wq1, const float* __restrict__ Wk1, const float* __restrict__ Wv,
    float* __restrict__ q1, float* __restrict__ k1, float* __restrict__ v1)
{
    __shared__ float lw[6144];
    for (int i=threadIdx.x; i<2048; i+=256){ lw[i]=Wq1[i]; lw[2048+i]=Wk1[i]; lw[4096+i]=Wv[i]; }
    __syncthreads();
    int t = threadIdx.x;
    int posIdx = blockIdx.x*64 + (t&63);
    int g = t>>6;                      // 4 channel-groups of 24
    int b = posIdx / NPOS, pos = posIdx % NPOS;
    int d = pos / HWP, pix = pos % HWP;
    float fac = 1.f;
    if (a[b*HWP+pix] == d) fac += wt[b*HWP+pix];
    float acc[24];
    #pragma unroll
    for (int j=0;j<24;++j) acc[j]=0.f;
    const float* xb = x + (size_t)b*CIN*NPOS + pos;
    int chBase = g*24;
    for (int c=0;c<CIN;++c){
        float xv = xb[(size_t)c*NPOS];
        const float* wrow = &lw[chBase*64 + c];
        #pragma unroll
        for (int j=0;j<24;++j) acc[j] += xv * wrow[j*64];
    }
    #pragma unroll
    for (int j=0;j<24;++j){
        int ch = chBase + j;
        float val = acc[j];
        if (ch < 32)       q1[((size_t)b*CT + ch)*NPOS + pos] = val;
        else if (ch < 64)  k1[((size_t)b*CT + (ch-32))*NPOS + pos] = val*fac;
        else               v1[((size_t)b*CT + (ch-64))*NPOS + pos] = val*fac;
    }
}

// ---------- per-channel BN stats: mu, rsqrt(var+eps) ----------
__global__ __launch_bounds__(256) void stats_kernel(const float* __restrict__ src,
                                                    float* __restrict__ mu, float* __restrict__ rs, int C)
{
    int ch = blockIdx.x;
    float sum=0.f, sq=0.f;
    for (int i=threadIdx.x; i<SAMP; i+=256){
        int b = i/NPOS; int pos = i - b*NPOS;
        float v = src[((size_t)b*C + ch)*NPOS + pos];
        sum += v; sq += v*v;
    }
    for (int off=32; off; off>>=1){ sum += __shfl_down(sum,off); sq += __shfl_down(sq,off); }
    __shared__ float ls[4], lq[4];
    int wv = threadIdx.x>>6, lane = threadIdx.x&63;
    if (lane==0){ ls[wv]=sum; lq[wv]=sq; }
    __syncthreads();
    if (threadIdx.x==0){
        float S = ls[0]+ls[1]+ls[2]+ls[3];
        float Q = lq[0]+lq[1]+lq[2]+lq[3];
        float m = S/(float)SAMP;
        float var = Q/(float)SAMP - m*m;
        mu[ch]=m; rs[ch]=rsqrtf(var + 1e-5f);
    }
}

// ---------- K5: conv2 (BN+ReLU of inputs fused): q2 = Wq2@bnrelu(q1), k2 = Wk2@bnrelu(k1) ----------
__global__ __launch_bounds__(256) void conv2_kernel(const float* __restrict__ q1, const float* __restrict__ k1,
    const float* __restrict__ Wq2, const float* __restrict__ Wk2,
    const float* __restrict__ mu1, const float* __restrict__ rs1,
    float* __restrict__ q2, float* __restrict__ k2)
{
    __shared__ float lw[2048];
    for (int i=threadIdx.x; i<1024; i+=256){ lw[i]=Wq2[i]; lw[1024+i]=Wk2[i]; }
    __syncthreads();
    int t = threadIdx.x;
    int posIdx = blockIdx.x*64 + (t&63);
    int g = t>>6;
    int b = posIdx / NPOS, pos = posIdx % NPOS;
    const float* src = (g<2) ? q1 : k1;
    const float* wb  = (g<2) ? lw : (lw+1024);
    float* dst       = (g<2) ? q2 : k2;
    int so = (g<2) ? 0 : 32;
    int chBase = (g&1)*16;
    float acc[16];
    #pragma unroll
    for (int j=0;j<16;++j) acc[j]=0.f;
    for (int c=0;c<32;++c){
        float v = src[((size_t)b*CT + c)*NPOS + pos];
        float vn = fmaxf((v - mu1[so+c])*rs1[so+c], 0.f);
        const float* wrow = &wb[chBase*32 + c];
        #pragma unroll
        for (int j=0;j<16;++j) acc[j] += vn * wrow[j*32];
    }
    #pragma unroll
    for (int j=0;j<16;++j)
        dst[((size_t)b*CT + chBase + j)*NPOS + pos] = acc[j];
}

// ---------- pack Q/K to bf16 [b][pos][ch] with BN+ReLU (+scale for Q) ----------
__global__ __launch_bounds__(256) void pack_qk_kernel(const float* __restrict__ q2, const float* __restrict__ k2,
    const float* __restrict__ mu2, const float* __restrict__ rs2,
    ushort* __restrict__ Qbf, ushort* __restrict__ Kbf)
{
    int idx = blockIdx.x*256 + threadIdx.x;   // 0..19199 (b*9600+pos)
    int b = idx / NPOS, pos = idx - b*NPOS;
    const float* qsrc = q2 + (size_t)b*CT*NPOS + pos;
    const float* ksrc = k2 + (size_t)b*CT*NPOS + pos;
    unsigned qw[16], kw[16];
    #pragma unroll
    for (int c2=0; c2<16; ++c2){
        int c0 = 2*c2, c1 = 2*c2+1;
        float a0 = fmaxf((qsrc[(size_t)c0*NPOS] - mu2[c0])*rs2[c0], 0.f)*QKSCALE;
        float a1 = fmaxf((qsrc[(size_t)c1*NPOS] - mu2[c1])*rs2[c1], 0.f)*QKSCALE;
        qw[c2] = (unsigned)f2bf(a0) | ((unsigned)f2bf(a1)<<16);
        float b0 = fmaxf((ksrc[(size_t)c0*NPOS] - mu2[32+c0])*rs2[32+c0], 0.f);
        float b1 = fmaxf((ksrc[(size_t)c1*NPOS] - mu2[32+c1])*rs2[32+c1], 0.f);
        kw[c2] = (unsigned)f2bf(b0) | ((unsigned)f2bf(b1)<<16);
    }
    uint4* qd = (uint4*)(Qbf + (size_t)idx*CT);
    uint4* kd = (uint4*)(Kbf + (size_t)idx*CT);
    #pragma unroll
    for (int j=0;j<4;++j){
        qd[j] = make_uint4(qw[4*j], qw[4*j+1], qw[4*j+2], qw[4*j+3]);
        kd[j] = make_uint4(kw[4*j], kw[4*j+1], kw[4*j+2], kw[4*j+3]);
    }
}

// ---------- pack V to bf16 [b][ch][pos] with BN+ReLU ----------
__global__ __launch_bounds__(256) void pack_v_kernel(const float* __restrict__ v1,
    const float* __restrict__ mu, const float* __restrict__ rs, ushort* __restrict__ Vbf)
{
    int i2 = blockIdx.x*256 + threadIdx.x;    // pair index 0..307199
    int idx = i2*2;
    int ch = (idx / NPOS) % CT;
    float m = mu[ch], r = rs[ch];
    float a0 = fmaxf((v1[idx]   - m)*r, 0.f);
    float a1 = fmaxf((v1[idx+1] - m)*r, 0.f);
    *(unsigned*)(Vbf + idx) = (unsigned)f2bf(a0) | ((unsigned)f2bf(a1)<<16);
}

// ---------- K7: MFMA flash attention, fixed-shift softmax, 1 wave / 16 queries ----------
__global__ __launch_bounds__(64) void attn_kernel(const ushort* __restrict__ Qbf,
    const ushort* __restrict__ Kbf, const ushort* __restrict__ Vbf, float* __restrict__ ctx)
{
    __shared__ ushort Pl[2][16][36];           // [dbuf][query][key] bf16, pad 36
    int blk = blockIdx.x;
    int b = blk / 600, qb = blk % 600;
    int q0 = qb * 16;
    int l = threadIdx.x;
    int g = l >> 4, col = l & 15;

    const ushort* Qb = Qbf + (size_t)b*NPOS*CT;
    const ushort* Kb = Kbf + (size_t)b*NPOS*CT;
    const ushort* V0 = Vbf + ((size_t)b*CT + col)*NPOS;       // ch = col
    const ushort* V1 = Vbf + ((size_t)b*CT + 16 + col)*NPOS;  // ch = col+16

    union U { uint4 u; short8 s; ushort4 h[2]; };
    U qf; qf.u = *(const uint4*)&Qb[(size_t)(q0+col)*CT + 8*g];   // B-frag: Q^T

    f32x4 acc0 = {0.f,0.f,0.f,0.f}, acc1 = {0.f,0.f,0.f,0.f};
    const f32x4 cinit = {-CSH, -CSH, -CSH, -CSH};
    float lsum = 0.f;

    U nk0, nk1, nv0, nv1;
    nk0.u = *(const uint4*)&Kb[(size_t)(col)*CT + 8*g];
    nk1.u = *(const uint4*)&Kb[(size_t)(16+col)*CT + 8*g];
    nv0.u = *(const uint4*)&V0[8*g];
    nv1.u = *(const uint4*)&V1[8*g];

    for (int chunk=0; chunk<300; ++chunk){
        U k0 = nk0, k1 = nk1, v0 = nv0, v1 = nv1;
        int nkey = (chunk < 299) ? (chunk+1)*32 : 299*32;      // clamp: redundant last prefetch
        nk0.u = *(const uint4*)&Kb[(size_t)(nkey+col)*CT + 8*g];
        nk1.u = *(const uint4*)&Kb[(size_t)(nkey+16+col)*CT + 8*g];
        nv0.u = *(const uint4*)&V0[nkey + 8*g];
        nv1.u = *(const uint4*)&V1[nkey + 8*g];

        // S^T tiles: rows = keys, cols = queries; C-init bakes in the -8 shift
        f32x4 s0 = __builtin_amdgcn_mfma_f32_16x16x32_bf16(k0.s, qf.s, cinit, 0, 0, 0);
        f32x4 s1 = __builtin_amdgcn_mfma_f32_16x16x32_bf16(k1.s, qf.s, cinit, 0, 0, 0);

        ushort4 w0, w1;
        float p;
        p = exp2f(s0.x); lsum += p; w0.x = f2bf(p);
        p = exp2f(s0.y); lsum += p; w0.y = f2bf(p);
        p = exp2f(s0.z); lsum += p; w0.z = f2bf(p);
        p = exp2f(s0.w); lsum += p; w0.w = f2bf(p);
        p = exp2f(s1.x); lsum += p; w1.x = f2bf(p);
        p = exp2f(s1.y); lsum += p; w1.y = f2bf(p);
        p = exp2f(s1.z); lsum += p; w1.z = f2bf(p);
        p = exp2f(s1.w); lsum += p; w1.w = f2bf(p);

        int buf = chunk & 1;
        // lane holds keys 4g..4g+3 (tile0) and 16+4g.. (tile1) of query 'col'
        *(ushort4*)&Pl[buf][col][4*g]    = w0;
        *(ushort4*)&Pl[buf][col][16+4*g] = w1;
        // B-frag for PV: P[col][8g..8g+7] (cross-lane within wave; lgkmcnt only)
        U pf;
        pf.h[0] = *(ushort4*)&Pl[buf][col][8*g];
        pf.h[1] = *(ushort4*)&Pl[buf][col][8*g+4];

        acc0 = __builtin_amdgcn_mfma_f32_16x16x32_bf16(v0.s, pf.s, acc0, 0, 0, 0);
        acc1 = __builtin_amdgcn_mfma_f32_16x16x32_bf16(v1.s, pf.s, acc1, 0, 0, 0);
    }

    // total l per query col: combine the 4 row-groups
    lsum += __shfl_xor(lsum, 16);
    lsum += __shfl_xor(lsum, 32);
    float inv = 1.f / lsum;

    float* cb = ctx + (size_t)b*CT*NPOS + q0 + col;
    #pragma unroll
    for (int r=0;r<4;++r){
        cb[(size_t)(4*g + r)*NPOS]      = acc0[r] * inv;
        cb[(size_t)(16 + 4*g + r)*NPOS] = acc1[r] * inv;
    }
}

// ---------- K8: out conv (raw): outraw = Wo @ ctx ----------
__global__ __launch_bounds__(256) void convo_kernel(const float* __restrict__ ctx,
    const float* __restrict__ Wo, float* __restrict__ outraw)
{
    __shared__ float lw[2048];
    for (int i=threadIdx.x; i<2048; i+=256) lw[i]=Wo[i];
    __syncthreads();
    int t = threadIdx.x;
    int posIdx = blockIdx.x*64 + (t&63);
    int g = t>>6;
    int b = posIdx / NPOS, pos = posIdx % NPOS;
    int chBase = g*16;
    float acc[16];
    #pragma unroll
    for (int j=0;j<16;++j) acc[j]=0.f;
    for (int c=0;c<32;++c){
        float v = ctx[((size_t)b*CT + c)*NPOS + pos];
        const float* wrow = &lw[chBase*32 + c];
        #pragma unroll
        for (int j=0;j<16;++j) acc[j] += v * wrow[j*32];
    }
    #pragma unroll
    for (int j=0;j<16;++j)
        outraw[((size_t)b*64 + chBase + j)*NPOS + pos] = acc[j];
}

// ---------- elementwise BN+ReLU ----------
__global__ __launch_bounds__(256) void bn_relu_kernel(const float* __restrict__ src,
    const float* __restrict__ mu, const float* __restrict__ rs,
    float* __restrict__ dst, int C, int total)
{
    int idx = blockIdx.x*256 + threadIdx.x;
    if (idx >= total) return;
    int ch = (idx / NPOS) % C;
    dst[idx] = fmaxf((src[idx]-mu[ch])*rs[ch], 0.f);
}

extern "C" void kernel_launch(void* const* d_in, const int* in_sizes, int n_in,
                              void* d_out, int out_size, void* d_ws, size_t ws_size,
                              hipStream_t stream)
{
    const float* x     = (const float*)d_in[0];
    const float* preds = (const float*)d_in[1];
    const float* Wq1   = (const float*)d_in[2];
    const float* Wq2   = (const float*)d_in[3];
    const float* Wk1   = (const float*)d_in[4];
    const float* Wk2   = (const float*)d_in[5];
    const float* Wv    = (const float*)d_in[6];
    const float* Wo    = (const float*)d_in[7];
    float* out = (float*)d_out;

    float* w     = (float*)d_ws;
    int*   a_idx = (int*)d_ws;            // [0, 1600)
    float* pv    = w + 2048;
    float* wt    = w + 4096;
    float* mu1   = w + 6656;  // 96
    float* rs1   = w + 6752;  // 96
    float* mu2   = w + 6848;  // 64 (q2:0..31, k2:32..63)
    float* rs2   = w + 6912;
    float* muo   = w + 6976;
    float* rso   = w + 7040;
    float* q1    = w + 8192;      // 614400 floats each
    float* k1    = w + 622592;
    float* v1    = w + 1236992;
    float* q2    = w + 1851392;
    float* k2    = w + 2465792;
    // bf16 tensors (after q1/k1/v1 retire):
    ushort* Qbf  = (ushort*)(w + 8192);        // 307200 f32-equiv, in q1 slot
    ushort* Kbf  = (ushort*)(w + 315392);      // second half of q1 slot
    ushort* Vbf  = (ushort*)(w + 3080192);     // old vnb slot
    float* ctx    = k1;                        // k1 dead after conv2
    float* outraw = v1;                        // v1+q2 slots dead after pack; 1228800 floats

    prep_kernel <<<7,   256,0,stream>>>(preds, a_idx, pv);
    seg_kernel  <<<24,  256,0,stream>>>(pv, a_idx, wt);
    conv1_kernel<<<300, 256,0,stream>>>(x, a_idx, wt, Wq1, Wk1, Wv, q1, k1, v1);
    stats_kernel<<<32,  256,0,stream>>>(q1, mu1,    rs1,    32);
    stats_kernel<<<32,  256,0,stream>>>(k1, mu1+32, rs1+32, 32);
    stats_kernel<<<32,  256,0,stream>>>(v1, mu1+64, rs1+64, 32);
    conv2_kernel<<<300, 256,0,stream>>>(q1, k1, Wq2, Wk2, mu1, rs1, q2, k2);
    stats_kernel<<<32,  256,0,stream>>>(q2, mu2,    rs2,    32);
    stats_kernel<<<32,  256,0,stream>>>(k2, mu2+32, rs2+32, 32);
    pack_qk_kernel<<<75,  256,0,stream>>>(q2, k2, mu2, rs2, Qbf, Kbf);
    pack_v_kernel <<<1200,256,0,stream>>>(v1, mu1+64, rs1+64, Vbf);
    attn_kernel <<<1200, 64,0,stream>>>(Qbf, Kbf, Vbf, ctx);
    convo_kernel<<<300, 256,0,stream>>>(ctx, Wo, outraw);
    stats_kernel<<<64,  256,0,stream>>>(outraw, muo, rso, 64);
    bn_relu_kernel<<<4800,256,0,stream>>>(outraw, muo, rso, out, 64, 1228800);
}

// Round 5
// 220.866 us; speedup vs baseline: 8.1135x; 1.5114x over previous
//
#include <hip/hip_runtime.h>

#define NB 2
#define CIN 64
#define DD 12
#define HWP 800
#define NPOS 9600   // DD*HWP
#define CT 32
#define QKSCALE 0.25506601f   // (1/sqrt(32)) * log2(e)  folded into Q pack
#define CSH 11.541560327f     // 8 * log2(e): P = exp2(S*log2e - CSH) = exp(S - 8)

typedef __attribute__((ext_vector_type(8))) short short8;
typedef __attribute__((ext_vector_type(4))) float f32x4;

__device__ __forceinline__ ushort f2bf(float x){
    union { float f; unsigned u; } v; v.f = x;
    unsigned r = v.u + 0x7fffu + ((v.u >> 16) & 1u);   // RNE
    return (ushort)(r >> 16);
}

// ---------- K1: per-pixel softmax over D, argmax, gathered prob ----------
__global__ __launch_bounds__(256) void prep_kernel(const float* __restrict__ preds,
                                                   int* __restrict__ a, float* __restrict__ pv)
{
    int idx = blockIdx.x*256 + threadIdx.x;
    if (idx >= NB*HWP) return;
    int b = idx / HWP, pix = idx % HWP;
    const float* p = preds + (size_t)b*DD*HWP + pix;
    float mx = -INFINITY; int am = 0;
    #pragma unroll
    for (int d=0; d<DD; ++d){ float v = p[d*HWP]; if (v > mx){ mx=v; am=d; } }
    float s = 0.f;
    #pragma unroll
    for (int d=0; d<DD; ++d) s += __expf(p[d*HWP]-mx);
    a[idx] = am; pv[idx] = 1.f/s;   // p[argmax] = exp(0)/s
}

// ---------- K2: segment softmax over pixels sharing argmax class ----------
__global__ __launch_bounds__(256) void seg_kernel(const float* __restrict__ pv,
                                                  const int* __restrict__ a, float* __restrict__ wt)
{
    int b = blockIdx.x / DD, seg = blockIdx.x % DD;
    int base = b*HWP;
    __shared__ float red[256];
    int t = threadIdx.x;
    float mx = -INFINITY;
    for (int i=t; i<HWP; i+=256) if (a[base+i]==seg) mx = fmaxf(mx, pv[base+i]);
    red[t]=mx; __syncthreads();
    for (int s=128; s>0; s>>=1){ if (t<s) red[t]=fmaxf(red[t],red[t+s]); __syncthreads(); }
    float m = red[0]; __syncthreads();
    if (m == -INFINITY) return;           // empty segment (uniform branch)
    float sm = 0.f;
    for (int i=t; i<HWP; i+=256) if (a[base+i]==seg) sm += __expf(pv[base+i]-m);
    red[t]=sm; __syncthreads();
    for (int s=128; s>0; s>>=1){ if (t<s) red[t]+=red[t+s]; __syncthreads(); }
    float ssum = red[0];
    for (int i=t; i<HWP; i+=256) if (a[base+i]==seg) wt[base+i] = __expf(pv[base+i]-m)/ssum;
}

// ---------- K3: fused conv1 + BN-stats partials ----------
__global__ __launch_bounds__(256) void conv1_kernel(const float* __restrict__ x,
    const int* __restrict__ a, const float* __restrict__ wt,
    const float* __restrict__ Wq1, const float* __restrict__ Wk1, const float* __restrict__ Wv,
    float* __restrict__ q1, float* __restrict__ k1, float* __restrict__ v1,
    float* __restrict__ part)
{
    __shared__ float lw[6144];
    for (int i=threadIdx.x; i<2048; i+=256){ lw[i]=Wq1[i]; lw[2048+i]=Wk1[i]; lw[4096+i]=Wv[i]; }
    __syncthreads();
    int t = threadIdx.x;
    int posIdx = blockIdx.x*64 + (t&63);
    int g = t>>6;                      // 4 channel-groups of 24 (one per wave)
    int b = posIdx / NPOS, pos = posIdx % NPOS;
    int d = pos / HWP, pix = pos % HWP;
    float fac = 1.f;
    if (a[b*HWP+pix] == d) fac += wt[b*HWP+pix];
    float acc[24];
    #pragma unroll
    for (int j=0;j<24;++j) acc[j]=0.f;
    const float* xb = x + (size_t)b*CIN*NPOS + pos;
    int chBase = g*24;
    for (int c=0;c<CIN;++c){
        float xv = xb[(size_t)c*NPOS];
        const float* wrow = &lw[chBase*64 + c];
        #pragma unroll
        for (int j=0;j<24;++j) acc[j] += xv * wrow[j*64];
    }
    #pragma unroll
    for (int j=0;j<24;++j){
        int ch = chBase + j;
        float val = acc[j];
        if (ch >= 32) val *= fac;
        acc[j] = val;
        if (ch < 32)       q1[((size_t)b*CT + ch)*NPOS + pos] = val;
        else if (ch < 64)  k1[((size_t)b*CT + (ch-32))*NPOS + pos] = val;
        else               v1[((size_t)b*CT + (ch-64))*NPOS + pos] = val;
    }
    // per-wave stats partials (64 positions per wave)
    #pragma unroll
    for (int j=0;j<24;++j){
        float s = acc[j], qs = acc[j]*acc[j];
        #pragma unroll
        for (int off=32; off; off>>=1){ s += __shfl_xor(s,off); qs += __shfl_xor(qs,off); }
        if ((t&63)==0){
            int ch = chBase+j;
            part[((size_t)ch*300 + blockIdx.x)*2]   = s;
            part[((size_t)ch*300 + blockIdx.x)*2+1] = qs;
        }
    }
}

// ---------- finalize stats: one block per channel ----------
__global__ __launch_bounds__(64) void statsfin_kernel(const float* __restrict__ part,
    float* __restrict__ mu, float* __restrict__ rs, int nblk)
{
    int ch = blockIdx.x;
    float s=0.f, q=0.f;
    for (int i=threadIdx.x; i<nblk; i+=64){
        s += part[((size_t)ch*nblk+i)*2];
        q += part[((size_t)ch*nblk+i)*2+1];
    }
    #pragma unroll
    for (int off=32; off; off>>=1){ s += __shfl_xor(s,off); q += __shfl_xor(q,off); }
    if (threadIdx.x==0){
        float m = s/19200.f;
        mu[ch]=m; rs[ch]=rsqrtf(q/19200.f - m*m + 1e-5f);
    }
}

// ---------- K5: conv2 (BN+ReLU fused on inputs) + stats partials ----------
__global__ __launch_bounds__(256) void conv2_kernel(const float* __restrict__ q1, const float* __restrict__ k1,
    const float* __restrict__ Wq2, const float* __restrict__ Wk2,
    const float* __restrict__ mu1, const float* __restrict__ rs1,
    float* __restrict__ q2, float* __restrict__ k2, float* __restrict__ part)
{
    __shared__ float lw[2048];
    for (int i=threadIdx.x; i<1024; i+=256){ lw[i]=Wq2[i]; lw[1024+i]=Wk2[i]; }
    __syncthreads();
    int t = threadIdx.x;
    int posIdx = blockIdx.x*64 + (t&63);
    int g = t>>6;
    int b = posIdx / NPOS, pos = posIdx % NPOS;
    const float* src = (g<2) ? q1 : k1;
    const float* wb  = (g<2) ? lw : (lw+1024);
    float* dst       = (g<2) ? q2 : k2;
    int so = (g<2) ? 0 : 32;
    int chBase = (g&1)*16;
    float acc[16];
    #pragma unroll
    for (int j=0;j<16;++j) acc[j]=0.f;
    for (int c=0;c<32;++c){
        float v = src[((size_t)b*CT + c)*NPOS + pos];
        float vn = fmaxf((v - mu1[so+c])*rs1[so+c], 0.f);
        const float* wrow = &wb[chBase*32 + c];
        #pragma unroll
        for (int j=0;j<16;++j) acc[j] += vn * wrow[j*32];
    }
    #pragma unroll
    for (int j=0;j<16;++j)
        dst[((size_t)b*CT + chBase + j)*NPOS + pos] = acc[j];
    #pragma unroll
    for (int j=0;j<16;++j){
        float s = acc[j], qs = acc[j]*acc[j];
        #pragma unroll
        for (int off=32; off; off>>=1){ s += __shfl_xor(s,off); qs += __shfl_xor(qs,off); }
        if ((t&63)==0){
            int ch = g*16+j;   // 0..31 = q2, 32..63 = k2
            part[((size_t)ch*300 + blockIdx.x)*2]   = s;
            part[((size_t)ch*300 + blockIdx.x)*2+1] = qs;
        }
    }
}

// ---------- pack Q/K to bf16 [b][pos][ch] with BN+ReLU (+scale for Q) ----------
__global__ __launch_bounds__(256) void pack_qk_kernel(const float* __restrict__ q2, const float* __restrict__ k2,
    const float* __restrict__ mu2, const float* __restrict__ rs2,
    ushort* __restrict__ Qbf, ushort* __restrict__ Kbf)
{
    int idx = blockIdx.x*256 + threadIdx.x;   // 0..19199 (b*9600+pos)
    int b = idx / NPOS, pos = idx - b*NPOS;
    const float* qsrc = q2 + (size_t)b*CT*NPOS + pos;
    const float* ksrc = k2 + (size_t)b*CT*NPOS + pos;
    unsigned qw[16], kw[16];
    #pragma unroll
    for (int c2=0; c2<16; ++c2){
        int c0 = 2*c2, c1 = 2*c2+1;
        float a0 = fmaxf((qsrc[(size_t)c0*NPOS] - mu2[c0])*rs2[c0], 0.f)*QKSCALE;
        float a1 = fmaxf((qsrc[(size_t)c1*NPOS] - mu2[c1])*rs2[c1], 0.f)*QKSCALE;
        qw[c2] = (unsigned)f2bf(a0) | ((unsigned)f2bf(a1)<<16);
        float b0 = fmaxf((ksrc[(size_t)c0*NPOS] - mu2[32+c0])*rs2[32+c0], 0.f);
        float b1 = fmaxf((ksrc[(size_t)c1*NPOS] - mu2[32+c1])*rs2[32+c1], 0.f);
        kw[c2] = (unsigned)f2bf(b0) | ((unsigned)f2bf(b1)<<16);
    }
    uint4* qd = (uint4*)(Qbf + (size_t)idx*CT);
    uint4* kd = (uint4*)(Kbf + (size_t)idx*CT);
    #pragma unroll
    for (int j=0;j<4;++j){
        qd[j] = make_uint4(qw[4*j], qw[4*j+1], qw[4*j+2], qw[4*j+3]);
        kd[j] = make_uint4(kw[4*j], kw[4*j+1], kw[4*j+2], kw[4*j+3]);
    }
}

// ---------- pack V to bf16 [b][ch][pos] with BN+ReLU ----------
__global__ __launch_bounds__(256) void pack_v_kernel(const float* __restrict__ v1,
    const float* __restrict__ mu, const float* __restrict__ rs, ushort* __restrict__ Vbf)
{
    int i2 = blockIdx.x*256 + threadIdx.x;    // pair index 0..307199
    int idx = i2*2;
    int ch = (idx / NPOS) % CT;
    float m = mu[ch], r = rs[ch];
    float a0 = fmaxf((v1[idx]   - m)*r, 0.f);
    float a1 = fmaxf((v1[idx+1] - m)*r, 0.f);
    *(unsigned*)(Vbf + idx) = (unsigned)f2bf(a0) | ((unsigned)f2bf(a1)<<16);
}

// ---------- K7: MFMA flash attention, fixed-shift softmax ----------
// 256 threads = 4 waves; each wave owns a 2400-key slice (linear partials),
// one LDS merge at the end. XCD-swizzled so each batch's K/V pins to 4 XCDs.
__global__ __launch_bounds__(256) void attn_kernel(const ushort* __restrict__ Qbf,
    const ushort* __restrict__ Kbf, const ushort* __restrict__ Vbf, float* __restrict__ ctx)
{
    __shared__ ushort Pl[4][16][40];           // per-wave P^T tile, pad 40 (16B-aligned b128 reads)
    __shared__ float mrg[3][64][10];           // cross-wave merge: 8 acc + lsum
    int xcd = blockIdx.x & 7, within = blockIdx.x >> 3;
    int b = xcd >> 2;                          // batch pinned to XCD half
    int qb = (xcd & 3)*150 + within;           // 0..599
    int q0 = qb * 16;
    int t = threadIdx.x, wv = t>>6, l = t&63, g = l>>4, col = l&15;

    const ushort* Qb  = Qbf + (size_t)b*NPOS*CT;
    const ushort* Kc  = Kbf + (size_t)b*NPOS*CT + (size_t)col*CT + 8*g;
    const ushort* V0c = Vbf + ((size_t)b*CT + col)*NPOS + 8*g;
    const ushort* V1c = Vbf + ((size_t)b*CT + 16 + col)*NPOS + 8*g;

    union U { uint4 u; short8 s; };
    U qf; qf.u = *(const uint4*)&Qb[(size_t)(q0+col)*CT + 8*g];   // B-frag: Q^T

    f32x4 acc0 = {0.f,0.f,0.f,0.f}, acc1 = {0.f,0.f,0.f,0.f};
    const f32x4 cinit = {-CSH, -CSH, -CSH, -CSH};
    float lsum = 0.f;

    int key0 = wv*2400;
    U nk0, nk1, nv0, nv1;
    nk0.u = *(const uint4*)&Kc[(size_t)key0*CT];
    nk1.u = *(const uint4*)&Kc[(size_t)(key0+16)*CT];
    nv0.u = *(const uint4*)&V0c[key0];
    nv1.u = *(const uint4*)&V1c[key0];

    for (int ck=0; ck<75; ++ck){
        U k0=nk0, k1=nk1, v0=nv0, v1=nv1;
        int nkey = key0 + ((ck<74) ? (ck+1)*32 : 74*32);   // clamp: redundant last prefetch
        nk0.u = *(const uint4*)&Kc[(size_t)nkey*CT];
        nk1.u = *(const uint4*)&Kc[(size_t)(nkey+16)*CT];
        nv0.u = *(const uint4*)&V0c[nkey];
        nv1.u = *(const uint4*)&V1c[nkey];

        // S^T tiles (rows = keys, cols = queries); C-init bakes in the shift
        f32x4 s0 = __builtin_amdgcn_mfma_f32_16x16x32_bf16(k0.s, qf.s, cinit, 0, 0, 0);
        f32x4 s1 = __builtin_amdgcn_mfma_f32_16x16x32_bf16(k1.s, qf.s, cinit, 0, 0, 0);

        float p0=exp2f(s0.x), p1=exp2f(s0.y), p2=exp2f(s0.z), p3=exp2f(s0.w);
        float p4=exp2f(s1.x), p5=exp2f(s1.y), p6=exp2f(s1.z), p7=exp2f(s1.w);
        lsum += (p0+p1)+(p2+p3)+((p4+p5)+(p6+p7));
        unsigned w0lo,w0hi,w1lo,w1hi;
        asm("v_cvt_pk_bf16_f32 %0,%1,%2" : "=v"(w0lo) : "v"(p0), "v"(p1));
        asm("v_cvt_pk_bf16_f32 %0,%1,%2" : "=v"(w0hi) : "v"(p2), "v"(p3));
        asm("v_cvt_pk_bf16_f32 %0,%1,%2" : "=v"(w1lo) : "v"(p4), "v"(p5));
        asm("v_cvt_pk_bf16_f32 %0,%1,%2" : "=v"(w1hi) : "v"(p6), "v"(p7));

        *(uint2*)&Pl[wv][col][4*g]    = make_uint2(w0lo, w0hi);
        *(uint2*)&Pl[wv][col][16+4*g] = make_uint2(w1lo, w1hi);
        U pf; pf.u = *(const uint4*)&Pl[wv][col][8*g];   // P[col][8g..8g+7]

        acc0 = __builtin_amdgcn_mfma_f32_16x16x32_bf16(v0.s, pf.s, acc0, 0, 0, 0);
        acc1 = __builtin_amdgcn_mfma_f32_16x16x32_bf16(v1.s, pf.s, acc1, 0, 0, 0);
    }

    // per-wave l for query col (sum over the 4 g-groups)
    lsum += __shfl_xor(lsum, 16);
    lsum += __shfl_xor(lsum, 32);

    if (wv > 0){
        float* mb = &mrg[wv-1][l][0];
        mb[0]=acc0.x; mb[1]=acc0.y; mb[2]=acc0.z; mb[3]=acc0.w;
        mb[4]=acc1.x; mb[5]=acc1.y; mb[6]=acc1.z; mb[7]=acc1.w;
        mb[8]=lsum;
    }
    __syncthreads();
    if (wv == 0){
        #pragma unroll
        for (int w2=0; w2<3; ++w2){
            const float* mb = &mrg[w2][l][0];
            acc0.x+=mb[0]; acc0.y+=mb[1]; acc0.z+=mb[2]; acc0.w+=mb[3];
            acc1.x+=mb[4]; acc1.y+=mb[5]; acc1.z+=mb[6]; acc1.w+=mb[7];
            lsum += mb[8];
        }
        float inv = 1.f/lsum;
        float* cb = ctx + (size_t)b*CT*NPOS + q0 + col;
        #pragma unroll
        for (int r=0;r<4;++r){
            cb[(size_t)(4*g + r)*NPOS]      = acc0[r] * inv;
            cb[(size_t)(16 + 4*g + r)*NPOS] = acc1[r] * inv;
        }
    }
}

// ---------- K8: out conv (raw) + stats partials ----------
__global__ __launch_bounds__(256) void convo_kernel(const float* __restrict__ ctx,
    const float* __restrict__ Wo, float* __restrict__ outraw, float* __restrict__ part)
{
    __shared__ float lw[2048];
    for (int i=threadIdx.x; i<2048; i+=256) lw[i]=Wo[i];
    __syncthreads();
    int t = threadIdx.x;
    int posIdx = blockIdx.x*64 + (t&63);
    int g = t>>6;
    int b = posIdx / NPOS, pos = posIdx % NPOS;
    int chBase = g*16;
    float acc[16];
    #pragma unroll
    for (int j=0;j<16;++j) acc[j]=0.f;
    for (int c=0;c<32;++c){
        float v = ctx[((size_t)b*CT + c)*NPOS + pos];
        const float* wrow = &lw[chBase*32 + c];
        #pragma unroll
        for (int j=0;j<16;++j) acc[j] += v * wrow[j*32];
    }
    #pragma unroll
    for (int j=0;j<16;++j)
        outraw[((size_t)b*64 + chBase + j)*NPOS + pos] = acc[j];
    #pragma unroll
    for (int j=0;j<16;++j){
        float s = acc[j], qs = acc[j]*acc[j];
        #pragma unroll
        for (int off=32; off; off>>=1){ s += __shfl_xor(s,off); qs += __shfl_xor(qs,off); }
        if ((t&63)==0){
            int ch = chBase+j;
            part[((size_t)ch*300 + blockIdx.x)*2]   = s;
            part[((size_t)ch*300 + blockIdx.x)*2+1] = qs;
        }
    }
}

// ---------- elementwise BN+ReLU ----------
__global__ __launch_bounds__(256) void bn_relu_kernel(const float* __restrict__ src,
    const float* __restrict__ mu, const float* __restrict__ rs,
    float* __restrict__ dst, int C, int total)
{
    int idx = blockIdx.x*256 + threadIdx.x;
    if (idx >= total) return;
    int ch = (idx / NPOS) % C;
    dst[idx] = fmaxf((src[idx]-mu[ch])*rs[ch], 0.f);
}

extern "C" void kernel_launch(void* const* d_in, const int* in_sizes, int n_in,
                              void* d_out, int out_size, void* d_ws, size_t ws_size,
                              hipStream_t stream)
{
    const float* x     = (const float*)d_in[0];
    const float* preds = (const float*)d_in[1];
    const float* Wq1   = (const float*)d_in[2];
    const float* Wq2   = (const float*)d_in[3];
    const float* Wk1   = (const float*)d_in[4];
    const float* Wk2   = (const float*)d_in[5];
    const float* Wv    = (const float*)d_in[6];
    const float* Wo    = (const float*)d_in[7];
    float* out = (float*)d_out;

    float* w     = (float*)d_ws;
    int*   a_idx = (int*)d_ws;            // [0, 1600)
    float* pv    = w + 2048;
    float* wt    = w + 4096;
    float* mu1   = w + 6656;  // 96 (q1 0-31, k1 32-63, v1 64-95)
    float* rs1   = w + 6752;
    float* mu2   = w + 6848;  // 64 (q2 0-31, k2 32-63)
    float* rs2   = w + 6912;
    float* muo   = w + 6976;
    float* rso   = w + 7040;
    float* q1    = w + 8192;      // 614400 floats each
    float* k1    = w + 622592;
    float* v1    = w + 1236992;
    float* q2    = w + 1851392;
    float* k2    = w + 2465792;
    // bf16 tensors (q1 slot dead after conv2):
    ushort* Qbf  = (ushort*)(w + 8192);
    ushort* Kbf  = (ushort*)(w + 315392);
    ushort* Vbf  = (ushort*)(w + 3080192);     // 614400 ushorts
    float* ctx    = k1;                        // k1 dead after conv2
    float* outraw = v1;                        // v1+q2 dead after packs; 1228800 floats
    // stats partials (after Vbf: w+3387392)
    float* part1 = w + 3387392;   // 96*300*2
    float* part2 = w + 3444992;   // 64*300*2
    float* parto = w + 3483392;   // 64*300*2

    prep_kernel <<<7,   256,0,stream>>>(preds, a_idx, pv);
    seg_kernel  <<<24,  256,0,stream>>>(pv, a_idx, wt);
    conv1_kernel<<<300, 256,0,stream>>>(x, a_idx, wt, Wq1, Wk1, Wv, q1, k1, v1, part1);
    statsfin_kernel<<<96, 64,0,stream>>>(part1, mu1, rs1, 300);
    conv2_kernel<<<300, 256,0,stream>>>(q1, k1, Wq2, Wk2, mu1, rs1, q2, k2, part2);
    statsfin_kernel<<<64, 64,0,stream>>>(part2, mu2, rs2, 300);
    pack_qk_kernel<<<75,  256,0,stream>>>(q2, k2, mu2, rs2, Qbf, Kbf);
    pack_v_kernel <<<1200,256,0,stream>>>(v1, mu1+64, rs1+64, Vbf);
    attn_kernel <<<1200, 256,0,stream>>>(Qbf, Kbf, Vbf, ctx);
    convo_kernel<<<300, 256,0,stream>>>(ctx, Wo, outraw, parto);
    statsfin_kernel<<<64, 64,0,stream>>>(parto, muo, rso, 300);
    bn_relu_kernel<<<4800,256,0,stream>>>(outraw, muo, rso, out, 64, 1228800);
}

// Round 6
// 168.306 us; speedup vs baseline: 10.6472x; 1.3123x over previous
//
#include <hip/hip_runtime.h>

#define NB 2
#define CIN 64
#define DD 12
#define HWP 800
#define NPOS 9600   // DD*HWP
#define CT 32
#define QKSCALE 0.25506601f   // (1/sqrt(32)) * log2(e)  folded into Q pack
#define CSH 11.541560327f     // 8 * log2(e): P = exp2(S*log2e - CSH) = exp(S - 8)

typedef __attribute__((ext_vector_type(8))) short short8;
typedef __attribute__((ext_vector_type(4))) float f32x4;

__device__ __forceinline__ ushort f2bf(float x){
    union { float f; unsigned u; } v; v.f = x;
    unsigned r = v.u + 0x7fffu + ((v.u >> 16) & 1u);   // RNE
    return (ushort)(r >> 16);
}

// ---------- K1: per-pixel softmax over D, argmax, gathered prob ----------
__global__ __launch_bounds__(256) void prep_kernel(const float* __restrict__ preds,
                                                   int* __restrict__ a, float* __restrict__ pv)
{
    int idx = blockIdx.x*256 + threadIdx.x;
    if (idx >= NB*HWP) return;
    int b = idx / HWP, pix = idx % HWP;
    const float* p = preds + (size_t)b*DD*HWP + pix;
    float mx = -INFINITY; int am = 0;
    #pragma unroll
    for (int d=0; d<DD; ++d){ float v = p[d*HWP]; if (v > mx){ mx=v; am=d; } }
    float s = 0.f;
    #pragma unroll
    for (int d=0; d<DD; ++d) s += __expf(p[d*HWP]-mx);
    a[idx] = am; pv[idx] = 1.f/s;   // p[argmax] = exp(0)/s
}

// ---------- K2: segment softmax over pixels sharing argmax class ----------
__global__ __launch_bounds__(256) void seg_kernel(const float* __restrict__ pv,
                                                  const int* __restrict__ a, float* __restrict__ wt)
{
    int b = blockIdx.x / DD, seg = blockIdx.x % DD;
    int base = b*HWP;
    __shared__ float red[256];
    int t = threadIdx.x;
    float mx = -INFINITY;
    for (int i=t; i<HWP; i+=256) if (a[base+i]==seg) mx = fmaxf(mx, pv[base+i]);
    red[t]=mx; __syncthreads();
    for (int s=128; s>0; s>>=1){ if (t<s) red[t]=fmaxf(red[t],red[t+s]); __syncthreads(); }
    float m = red[0]; __syncthreads();
    if (m == -INFINITY) return;           // empty segment (uniform branch)
    float sm = 0.f;
    for (int i=t; i<HWP; i+=256) if (a[base+i]==seg) sm += __expf(pv[base+i]-m);
    red[t]=sm; __syncthreads();
    for (int s=128; s>0; s>>=1){ if (t<s) red[t]+=red[t+s]; __syncthreads(); }
    float ssum = red[0];
    for (int i=t; i<HWP; i+=256) if (a[base+i]==seg) wt[base+i] = __expf(pv[base+i]-m)/ssum;
}

// ---------- K3: fused conv1 + BN-stats partials ----------
__global__ __launch_bounds__(256) void conv1_kernel(const float* __restrict__ x,
    const int* __restrict__ a, const float* __restrict__ wt,
    const float* __restrict__ Wq1, const float* __restrict__ Wk1, const float* __restrict__ Wv,
    float* __restrict__ q1, float* __restrict__ k1, float* __restrict__ v1,
    float* __restrict__ part)
{
    __shared__ float lw[6144];
    for (int i=threadIdx.x; i<2048; i+=256){ lw[i]=Wq1[i]; lw[2048+i]=Wk1[i]; lw[4096+i]=Wv[i]; }
    __syncthreads();
    int t = threadIdx.x;
    int posIdx = blockIdx.x*64 + (t&63);
    int g = t>>6;                      // 4 channel-groups of 24 (one per wave)
    int b = posIdx / NPOS, pos = posIdx % NPOS;
    int d = pos / HWP, pix = pos % HWP;
    float fac = 1.f;
    if (a[b*HWP+pix] == d) fac += wt[b*HWP+pix];
    float acc[24];
    #pragma unroll
    for (int j=0;j<24;++j) acc[j]=0.f;
    const float* xb = x + (size_t)b*CIN*NPOS + pos;
    int chBase = g*24;
    for (int c=0;c<CIN;++c){
        float xv = xb[(size_t)c*NPOS];
        const float* wrow = &lw[chBase*64 + c];
        #pragma unroll
        for (int j=0;j<24;++j) acc[j] += xv * wrow[j*64];
    }
    #pragma unroll
    for (int j=0;j<24;++j){
        int ch = chBase + j;
        float val = acc[j];
        if (ch >= 32) val *= fac;
        acc[j] = val;
        if (ch < 32)       q1[((size_t)b*CT + ch)*NPOS + pos] = val;
        else if (ch < 64)  k1[((size_t)b*CT + (ch-32))*NPOS + pos] = val;
        else               v1[((size_t)b*CT + (ch-64))*NPOS + pos] = val;
    }
    // per-wave stats partials (64 positions per wave)
    #pragma unroll
    for (int j=0;j<24;++j){
        float s = acc[j], qs = acc[j]*acc[j];
        #pragma unroll
        for (int off=32; off; off>>=1){ s += __shfl_xor(s,off); qs += __shfl_xor(qs,off); }
        if ((t&63)==0){
            int ch = chBase+j;
            part[((size_t)ch*300 + blockIdx.x)*2]   = s;
            part[((size_t)ch*300 + blockIdx.x)*2+1] = qs;
        }
    }
}

// ---------- finalize stats: one block per channel ----------
__global__ __launch_bounds__(64) void statsfin_kernel(const float* __restrict__ part,
    float* __restrict__ mu, float* __restrict__ rs, int nblk)
{
    int ch = blockIdx.x;
    float s=0.f, q=0.f;
    for (int i=threadIdx.x; i<nblk; i+=64){
        s += part[((size_t)ch*nblk+i)*2];
        q += part[((size_t)ch*nblk+i)*2+1];
    }
    #pragma unroll
    for (int off=32; off; off>>=1){ s += __shfl_xor(s,off); q += __shfl_xor(q,off); }
    if (threadIdx.x==0){
        float m = s/19200.f;
        mu[ch]=m; rs[ch]=rsqrtf(q/19200.f - m*m + 1e-5f);
    }
}

// ---------- K5: conv2 (BN+ReLU fused on inputs) + stats partials ----------
__global__ __launch_bounds__(256) void conv2_kernel(const float* __restrict__ q1, const float* __restrict__ k1,
    const float* __restrict__ Wq2, const float* __restrict__ Wk2,
    const float* __restrict__ mu1, const float* __restrict__ rs1,
    float* __restrict__ q2, float* __restrict__ k2, float* __restrict__ part)
{
    __shared__ float lw[2048];
    for (int i=threadIdx.x; i<1024; i+=256){ lw[i]=Wq2[i]; lw[1024+i]=Wk2[i]; }
    __syncthreads();
    int t = threadIdx.x;
    int posIdx = blockIdx.x*64 + (t&63);
    int g = t>>6;
    int b = posIdx / NPOS, pos = posIdx % NPOS;
    const float* src = (g<2) ? q1 : k1;
    const float* wb  = (g<2) ? lw : (lw+1024);
    float* dst       = (g<2) ? q2 : k2;
    int so = (g<2) ? 0 : 32;
    int chBase = (g&1)*16;
    float acc[16];
    #pragma unroll
    for (int j=0;j<16;++j) acc[j]=0.f;
    for (int c=0;c<32;++c){
        float v = src[((size_t)b*CT + c)*NPOS + pos];
        float vn = fmaxf((v - mu1[so+c])*rs1[so+c], 0.f);
        const float* wrow = &wb[chBase*32 + c];
        #pragma unroll
        for (int j=0;j<16;++j) acc[j] += vn * wrow[j*32];
    }
    #pragma unroll
    for (int j=0;j<16;++j)
        dst[((size_t)b*CT + chBase + j)*NPOS + pos] = acc[j];
    #pragma unroll
    for (int j=0;j<16;++j){
        float s = acc[j], qs = acc[j]*acc[j];
        #pragma unroll
        for (int off=32; off; off>>=1){ s += __shfl_xor(s,off); qs += __shfl_xor(qs,off); }
        if ((t&63)==0){
            int ch = g*16+j;   // 0..31 = q2, 32..63 = k2
            part[((size_t)ch*300 + blockIdx.x)*2]   = s;
            part[((size_t)ch*300 + blockIdx.x)*2+1] = qs;
        }
    }
}

// ---------- pack Q/K to bf16 [b][pos][ch] with BN+ReLU (+scale for Q) ----------
__global__ __launch_bounds__(256) void pack_qk_kernel(const float* __restrict__ q2, const float* __restrict__ k2,
    const float* __restrict__ mu2, const float* __restrict__ rs2,
    ushort* __restrict__ Qbf, ushort* __restrict__ Kbf)
{
    int idx = blockIdx.x*256 + threadIdx.x;   // 0..19199 (b*9600+pos)
    int b = idx / NPOS, pos = idx - b*NPOS;
    const float* qsrc = q2 + (size_t)b*CT*NPOS + pos;
    const float* ksrc = k2 + (size_t)b*CT*NPOS + pos;
    unsigned qw[16], kw[16];
    #pragma unroll
    for (int c2=0; c2<16; ++c2){
        int c0 = 2*c2, c1 = 2*c2+1;
        float a0 = fmaxf((qsrc[(size_t)c0*NPOS] - mu2[c0])*rs2[c0], 0.f)*QKSCALE;
        float a1 = fmaxf((qsrc[(size_t)c1*NPOS] - mu2[c1])*rs2[c1], 0.f)*QKSCALE;
        qw[c2] = (unsigned)f2bf(a0) | ((unsigned)f2bf(a1)<<16);
        float b0 = fmaxf((ksrc[(size_t)c0*NPOS] - mu2[32+c0])*rs2[32+c0], 0.f);
        float b1 = fmaxf((ksrc[(size_t)c1*NPOS] - mu2[32+c1])*rs2[32+c1], 0.f);
        kw[c2] = (unsigned)f2bf(b0) | ((unsigned)f2bf(b1)<<16);
    }
    uint4* qd = (uint4*)(Qbf + (size_t)idx*CT);
    uint4* kd = (uint4*)(Kbf + (size_t)idx*CT);
    #pragma unroll
    for (int j=0;j<4;++j){
        qd[j] = make_uint4(qw[4*j], qw[4*j+1], qw[4*j+2], qw[4*j+3]);
        kd[j] = make_uint4(kw[4*j], kw[4*j+1], kw[4*j+2], kw[4*j+3]);
    }
}

// ---------- pack V to bf16 [b][ch][pos] with BN+ReLU ----------
__global__ __launch_bounds__(256) void pack_v_kernel(const float* __restrict__ v1,
    const float* __restrict__ mu, const float* __restrict__ rs, ushort* __restrict__ Vbf)
{
    int i2 = blockIdx.x*256 + threadIdx.x;    // pair index 0..307199
    int idx = i2*2;
    int ch = (idx / NPOS) % CT;
    float m = mu[ch], r = rs[ch];
    float a0 = fmaxf((v1[idx]   - m)*r, 0.f);
    float a1 = fmaxf((v1[idx+1] - m)*r, 0.f);
    *(unsigned*)(Vbf + idx) = (unsigned)f2bf(a0) | ((unsigned)f2bf(a1)<<16);
}

// ---------- K7: MFMA flash attention, fixed-shift softmax ----------
// 1200 blocks = 2 batches x 300 q-blocks(32 q) x 2 key-halves(4800).
// 4 waves per block, each a ~1200-key slice; 2 q-tiles per wave per iter.
// Linear partials (acc, lsum) -> merge_kernel combines the two halves.
__global__ __launch_bounds__(256) void attn_kernel(const ushort* __restrict__ Qbf,
    const ushort* __restrict__ Kbf, const ushort* __restrict__ Vbf,
    float* __restrict__ pacc, float* __restrict__ plsum)
{
    __shared__ ushort Pl[4][2][16][40];        // [wave][q-tile][query][keys] pad 40
    __shared__ float mrg[3][64][20];           // cross-wave merge: 16 acc + 2 lsum
    int xcd = blockIdx.x & 7, idx = blockIdx.x >> 3;
    int b = xcd >> 2;                          // batch pinned to XCD half
    int qb = (xcd & 3)*75 + idx%75;            // 0..299
    int half = idx/75;                         // key half
    int q0 = qb*32;
    int t = threadIdx.x, wv = t>>6, l = t&63, g = l>>4, col = l&15;

    const ushort* Qb  = Qbf + (size_t)b*NPOS*CT;
    const ushort* Kc  = Kbf + (size_t)b*NPOS*CT + (size_t)col*CT + 8*g;
    const ushort* V0c = Vbf + ((size_t)b*CT + col)*NPOS + 8*g;
    const ushort* V1c = Vbf + ((size_t)b*CT + 16 + col)*NPOS + 8*g;

    union U { uint4 u; short8 s; };
    U qf0, qf1;
    qf0.u = *(const uint4*)&Qb[(size_t)(q0+col)*CT + 8*g];
    qf1.u = *(const uint4*)&Qb[(size_t)(q0+16+col)*CT + 8*g];

    f32x4 acc00={0.f,0.f,0.f,0.f}, acc01=acc00, acc10=acc00, acc11=acc00;
    const f32x4 cinit = {-CSH, -CSH, -CSH, -CSH};
    float lsum0 = 0.f, lsum1 = 0.f;

    int key0 = half*4800 + wv*1216;            // slices 1216/1216/1216/1152
    int niter = (wv<3) ? 38 : 36;

    U nk0, nk1, nv0, nv1;
    nk0.u = *(const uint4*)&Kc[(size_t)key0*CT];
    nk1.u = *(const uint4*)&Kc[(size_t)(key0+16)*CT];
    nv0.u = *(const uint4*)&V0c[key0];
    nv1.u = *(const uint4*)&V1c[key0];

    for (int ck=0; ck<niter; ++ck){
        U k0=nk0, k1=nk1, v0=nv0, v1=nv1;
        int nk = key0 + ((ck+1<niter) ? (ck+1) : ck)*32;   // clamp: redundant last prefetch
        nk0.u = *(const uint4*)&Kc[(size_t)nk*CT];
        nk1.u = *(const uint4*)&Kc[(size_t)(nk+16)*CT];
        nv0.u = *(const uint4*)&V0c[nk];
        nv1.u = *(const uint4*)&V1c[nk];

        // S^T tiles: 4 MFMA (2 key-subtiles x 2 q-tiles), C-init bakes in shift
        f32x4 s00 = __builtin_amdgcn_mfma_f32_16x16x32_bf16(k0.s, qf0.s, cinit, 0, 0, 0);
        f32x4 s10 = __builtin_amdgcn_mfma_f32_16x16x32_bf16(k1.s, qf0.s, cinit, 0, 0, 0);
        f32x4 s01 = __builtin_amdgcn_mfma_f32_16x16x32_bf16(k0.s, qf1.s, cinit, 0, 0, 0);
        f32x4 s11 = __builtin_amdgcn_mfma_f32_16x16x32_bf16(k1.s, qf1.s, cinit, 0, 0, 0);

        // ---- q-tile 0 ----
        {
            float p0=exp2f(s00.x), p1=exp2f(s00.y), p2=exp2f(s00.z), p3=exp2f(s00.w);
            float p4=exp2f(s10.x), p5=exp2f(s10.y), p6=exp2f(s10.z), p7=exp2f(s10.w);
            lsum0 += (p0+p1)+(p2+p3)+((p4+p5)+(p6+p7));
            unsigned wa,wb2,wc,wd;
            asm("v_cvt_pk_bf16_f32 %0,%1,%2" : "=v"(wa) : "v"(p0), "v"(p1));
            asm("v_cvt_pk_bf16_f32 %0,%1,%2" : "=v"(wb2) : "v"(p2), "v"(p3));
            asm("v_cvt_pk_bf16_f32 %0,%1,%2" : "=v"(wc) : "v"(p4), "v"(p5));
            asm("v_cvt_pk_bf16_f32 %0,%1,%2" : "=v"(wd) : "v"(p6), "v"(p7));
            *(uint2*)&Pl[wv][0][col][4*g]    = make_uint2(wa, wb2);
            *(uint2*)&Pl[wv][0][col][16+4*g] = make_uint2(wc, wd);
            U pf; pf.u = *(const uint4*)&Pl[wv][0][col][8*g];
            acc00 = __builtin_amdgcn_mfma_f32_16x16x32_bf16(v0.s, pf.s, acc00, 0, 0, 0);
            acc01 = __builtin_amdgcn_mfma_f32_16x16x32_bf16(v1.s, pf.s, acc01, 0, 0, 0);
        }
        // ---- q-tile 1 ----
        {
            float p0=exp2f(s01.x), p1=exp2f(s01.y), p2=exp2f(s01.z), p3=exp2f(s01.w);
            float p4=exp2f(s11.x), p5=exp2f(s11.y), p6=exp2f(s11.z), p7=exp2f(s11.w);
            lsum1 += (p0+p1)+(p2+p3)+((p4+p5)+(p6+p7));
            unsigned wa,wb2,wc,wd;
            asm("v_cvt_pk_bf16_f32 %0,%1,%2" : "=v"(wa) : "v"(p0), "v"(p1));
            asm("v_cvt_pk_bf16_f32 %0,%1,%2" : "=v"(wb2) : "v"(p2), "v"(p3));
            asm("v_cvt_pk_bf16_f32 %0,%1,%2" : "=v"(wc) : "v"(p4), "v"(p5));
            asm("v_cvt_pk_bf16_f32 %0,%1,%2" : "=v"(wd) : "v"(p6), "v"(p7));
            *(uint2*)&Pl[wv][1][col][4*g]    = make_uint2(wa, wb2);
            *(uint2*)&Pl[wv][1][col][16+4*g] = make_uint2(wc, wd);
            U pf; pf.u = *(const uint4*)&Pl[wv][1][col][8*g];
            acc10 = __builtin_amdgcn_mfma_f32_16x16x32_bf16(v0.s, pf.s, acc10, 0, 0, 0);
            acc11 = __builtin_amdgcn_mfma_f32_16x16x32_bf16(v1.s, pf.s, acc11, 0, 0, 0);
        }
    }

    // per-wave l per query col (sum the 4 g-groups)
    lsum0 += __shfl_xor(lsum0, 16); lsum0 += __shfl_xor(lsum0, 32);
    lsum1 += __shfl_xor(lsum1, 16); lsum1 += __shfl_xor(lsum1, 32);

    if (wv > 0){
        float* mb = &mrg[wv-1][l][0];
        #pragma unroll
        for (int r=0;r<4;++r){ mb[r]=acc00[r]; mb[4+r]=acc01[r]; mb[8+r]=acc10[r]; mb[12+r]=acc11[r]; }
        mb[16]=lsum0; mb[17]=lsum1;
    }
    __syncthreads();
    if (wv == 0){
        #pragma unroll
        for (int w2=0; w2<3; ++w2){
            const float* mb = &mrg[w2][l][0];
            #pragma unroll
            for (int r=0;r<4;++r){ acc00[r]+=mb[r]; acc01[r]+=mb[4+r]; acc10[r]+=mb[8+r]; acc11[r]+=mb[12+r]; }
            lsum0 += mb[16]; lsum1 += mb[17];
        }
        float* pa = pacc + (size_t)(b*2 + half)*CT*NPOS;
        int pos0 = q0 + col, pos1 = q0 + 16 + col;
        #pragma unroll
        for (int r=0;r<4;++r){
            pa[(size_t)(4*g+r)*NPOS + pos0]      = acc00[r];
            pa[(size_t)(16+4*g+r)*NPOS + pos0]   = acc01[r];
            pa[(size_t)(4*g+r)*NPOS + pos1]      = acc10[r];
            pa[(size_t)(16+4*g+r)*NPOS + pos1]   = acc11[r];
        }
        if (g == 0){
            plsum[(size_t)(b*2+half)*NPOS + pos0] = lsum0;
            plsum[(size_t)(b*2+half)*NPOS + pos1] = lsum1;
        }
    }
}

// ---------- merge the two key-halves: ctx = (accA+accB)/(lA+lB) ----------
__global__ __launch_bounds__(256) void merge_kernel(const float* __restrict__ pacc,
    const float* __restrict__ plsum, float* __restrict__ ctx)
{
    int idx = blockIdx.x*256 + threadIdx.x;    // < NB*CT*NPOS = 614400
    int b = idx / (CT*NPOS);
    int within = idx - b*CT*NPOS;
    int pos = within % NPOS;
    float aA = pacc[(size_t)(b*2)*CT*NPOS + within];
    float aB = pacc[(size_t)(b*2+1)*CT*NPOS + within];
    float lA = plsum[(size_t)(b*2)*NPOS + pos];
    float lB = plsum[(size_t)(b*2+1)*NPOS + pos];
    ctx[idx] = (aA + aB) / (lA + lB);
}

// ---------- K8: out conv (raw) + stats partials ----------
__global__ __launch_bounds__(256) void convo_kernel(const float* __restrict__ ctx,
    const float* __restrict__ Wo, float* __restrict__ outraw, float* __restrict__ part)
{
    __shared__ float lw[2048];
    for (int i=threadIdx.x; i<2048; i+=256) lw[i]=Wo[i];
    __syncthreads();
    int t = threadIdx.x;
    int posIdx = blockIdx.x*64 + (t&63);
    int g = t>>6;
    int b = posIdx / NPOS, pos = posIdx % NPOS;
    int chBase = g*16;
    float acc[16];
    #pragma unroll
    for (int j=0;j<16;++j) acc[j]=0.f;
    for (int c=0;c<32;++c){
        float v = ctx[((size_t)b*CT + c)*NPOS + pos];
        const float* wrow = &lw[chBase*32 + c];
        #pragma unroll
        for (int j=0;j<16;++j) acc[j] += v * wrow[j*32];
    }
    #pragma unroll
    for (int j=0;j<16;++j)
        outraw[((size_t)b*64 + chBase + j)*NPOS + pos] = acc[j];
    #pragma unroll
    for (int j=0;j<16;++j){
        float s = acc[j], qs = acc[j]*acc[j];
        #pragma unroll
        for (int off=32; off; off>>=1){ s += __shfl_xor(s,off); qs += __shfl_xor(qs,off); }
        if ((t&63)==0){
            int ch = chBase+j;
            part[((size_t)ch*300 + blockIdx.x)*2]   = s;
            part[((size_t)ch*300 + blockIdx.x)*2+1] = qs;
        }
    }
}

// ---------- elementwise BN+ReLU ----------
__global__ __launch_bounds__(256) void bn_relu_kernel(const float* __restrict__ src,
    const float* __restrict__ mu, const float* __restrict__ rs,
    float* __restrict__ dst, int C, int total)
{
    int idx = blockIdx.x*256 + threadIdx.x;
    if (idx >= total) return;
    int ch = (idx / NPOS) % C;
    dst[idx] = fmaxf((src[idx]-mu[ch])*rs[ch], 0.f);
}

extern "C" void kernel_launch(void* const* d_in, const int* in_sizes, int n_in,
                              void* d_out, int out_size, void* d_ws, size_t ws_size,
                              hipStream_t stream)
{
    const float* x     = (const float*)d_in[0];
    const float* preds = (const float*)d_in[1];
    const float* Wq1   = (const float*)d_in[2];
    const float* Wq2   = (const float*)d_in[3];
    const float* Wk1   = (const float*)d_in[4];
    const float* Wk2   = (const float*)d_in[5];
    const float* Wv    = (const float*)d_in[6];
    const float* Wo    = (const float*)d_in[7];
    float* out = (float*)d_out;

    float* w     = (float*)d_ws;
    int*   a_idx = (int*)d_ws;            // [0, 1600)
    float* pv    = w + 2048;
    float* wt    = w + 4096;
    float* mu1   = w + 6656;  // 96 (q1 0-31, k1 32-63, v1 64-95)
    float* rs1   = w + 6752;
    float* mu2   = w + 6848;  // 64 (q2 0-31, k2 32-63)
    float* rs2   = w + 6912;
    float* muo   = w + 6976;
    float* rso   = w + 7040;
    float* q1    = w + 8192;      // 614400 floats each
    float* k1    = w + 622592;
    float* v1    = w + 1236992;
    float* q2    = w + 1851392;
    float* k2    = w + 2465792;
    // bf16 tensors (q1 slot dead after conv2):
    ushort* Qbf  = (ushort*)(w + 8192);
    ushort* Kbf  = (ushort*)(w + 315392);
    ushort* Vbf  = (ushort*)(w + 3080192);     // 614400 ushorts -> ends 3387392
    // attention partials: pacc reuses v1+q2 slots (exactly 1228800 floats)
    float* pacc  = w + 1236992;
    float* plsum = w + 3387392;   // 38400, reuses dead part1 region head
    float* ctx    = k1;           // k1 dead after conv2
    float* outraw = w + 1236992;  // pacc region, dead after merge
    // stats partials
    float* part1 = w + 3444992;   // 96*300*2 = 57600 -> ends 3502592
    float* part2 = w + 3502592;   // 64*300*2 = 38400 -> ends 3540992
    float* parto = w + 3540992;   // 38400 -> ends 3579392

    prep_kernel <<<7,   256,0,stream>>>(preds, a_idx, pv);
    seg_kernel  <<<24,  256,0,stream>>>(pv, a_idx, wt);
    conv1_kernel<<<300, 256,0,stream>>>(x, a_idx, wt, Wq1, Wk1, Wv, q1, k1, v1, part1);
    statsfin_kernel<<<96, 64,0,stream>>>(part1, mu1, rs1, 300);
    conv2_kernel<<<300, 256,0,stream>>>(q1, k1, Wq2, Wk2, mu1, rs1, q2, k2, part2);
    statsfin_kernel<<<64, 64,0,stream>>>(part2, mu2, rs2, 300);
    pack_qk_kernel<<<75,  256,0,stream>>>(q2, k2, mu2, rs2, Qbf, Kbf);
    pack_v_kernel <<<1200,256,0,stream>>>(v1, mu1+64, rs1+64, Vbf);
    attn_kernel <<<1200, 256,0,stream>>>(Qbf, Kbf, Vbf, pacc, plsum);
    merge_kernel<<<2400, 256,0,stream>>>(pacc, plsum, ctx);
    convo_kernel<<<300, 256,0,stream>>>(ctx, Wo, outraw, parto);
    statsfin_kernel<<<64, 64,0,stream>>>(parto, muo, rso, 300);
    bn_relu_kernel<<<4800,256,0,stream>>>(outraw, muo, rso, out, 64, 1228800);
}